// Round 20
// baseline (128.711 us; speedup 1.0000x reference)
//
#include <hip/hip_runtime.h>
#include <hip/hip_bf16.h>
#include <stdint.h>

#define TT 2048
#define CC 1024
#define NH 16
#define HD 64
#define QKVN 3072

typedef __attribute__((ext_vector_type(8))) short short8;
typedef __attribute__((ext_vector_type(4))) float floatx4;
typedef __attribute__((ext_vector_type(4))) unsigned short ushortx4;

typedef const __attribute__((address_space(1))) void gas_void;
typedef __attribute__((address_space(3))) void las_void;

// s_barrier that is ALSO a compiler memory fence (raw builtin is not -- R17 race).
__device__ __forceinline__ void barrier_fence() {
  asm volatile("s_barrier" ::: "memory");
}

__device__ __forceinline__ void gload16(const void* g, void* l) {
  __builtin_amdgcn_global_load_lds((gas_void*)g, (las_void*)l, 16, 0, 0);
}

__device__ __forceinline__ unsigned short f2bf(float f) {
  union { float f; uint32_t u; } v; v.f = f;
  uint32_t u = v.u;
  uint32_t r = (u + 0x7fffu + ((u >> 16) & 1u)) >> 16;
  return (unsigned short)r;
}

__device__ __forceinline__ float fexp2(float x) {
#if __has_builtin(__builtin_amdgcn_exp2f)
  return __builtin_amdgcn_exp2f(x);
#else
  return exp2f(x);
#endif
}

#define QSCALE 0.18033688011112042f  // (1/8)*log2(e), folded into Wq/bq

// kv permutation within a 64-block: chunk c'=4kk+g holds runs [kA..kA+3, kA+8..kA+11]
__device__ __forceinline__ int perm64(int t) {
  const int kk = t >> 5, r5 = t & 31;
  const int g = ((r5 >> 3) & 2) | ((r5 >> 2) & 1);
  const int slot = (r5 & 3) | ((r5 >> 1) & 4);
  return kk * 32 + g * 8 + slot;
}

// ---------------- fused f32 -> bf16 conversion (grid-stride); Wq pre-scaled -----------
__global__ __launch_bounds__(256) void cvt_fused(const float* __restrict__ x,
                                                 const float* __restrict__ wq,
                                                 const float* __restrict__ wk,
                                                 const float* __restrict__ wv,
                                                 const float* __restrict__ wp,
                                                 unsigned short* __restrict__ xb,
                                                 unsigned short* __restrict__ wqkvb,
                                                 unsigned short* __restrict__ wpb) {
  for (int i = blockIdx.x * 256 + threadIdx.x; i < 2097152; i += 2048 * 256) {
    if (i < 1048576) {            // x: 4096x1024
      const float4 v = reinterpret_cast<const float4*>(x)[i];
      ushortx4 o; o[0] = f2bf(v.x); o[1] = f2bf(v.y); o[2] = f2bf(v.z); o[3] = f2bf(v.w);
      reinterpret_cast<ushortx4*>(xb)[i] = o;
      continue;
    }
    const int j = i - 1048576;     // 0..1048575 over 4 weight matrices
    const int seg = j >> 18;       // 262144 f4 per weight
    const int idx = j & 262143;
    const float* src = (seg == 0) ? wq : (seg == 1) ? wk : (seg == 2) ? wv : wp;
    const float sc = (seg == 0) ? QSCALE : 1.0f;
    const float4 v = reinterpret_cast<const float4*>(src)[idx];
    ushortx4 o;
    o[0] = f2bf(v.x * sc); o[1] = f2bf(v.y * sc); o[2] = f2bf(v.z * sc); o[3] = f2bf(v.w * sc);
    if (seg < 3)
      reinterpret_cast<ushortx4*>(wqkvb)[j] = o;       // q,k,v contiguous thirds
    else
      reinterpret_cast<ushortx4*>(wpb)[idx] = o;
  }
}

// ---------------- QKV GEMM: 128x192 tile, grid 512 = 2 blocks/CU, XCD-chunked ---------
// 4 waves 1x4; per-wave 128x48 (acc 8x3). LDS 80 KB double-buffered -> exactly
// 2 blocks/CU; two blocks' barrier phases interleave (latency hiding, cf. proj R19).
// Counted-vmcnt 2-deep (vmcnt(10): 4 A + 6 B gload16 per wave per tile).
__global__ __launch_bounds__(256) void gemm_qkv(const unsigned short* __restrict__ A,
                                                const unsigned short* __restrict__ W,
                                                const float* __restrict__ b0,
                                                const float* __restrict__ b1,
                                                const float* __restrict__ b2,
                                                unsigned short* __restrict__ out,
                                                unsigned short* __restrict__ Vt) {
  __shared__ unsigned short lsA[2][128 * 64];
  __shared__ unsigned short lsB[2][192 * 64];
  const int tid = threadIdx.x;
  const int wave = tid >> 6, lane = tid & 63;
  const int g = lane >> 4, c16 = lane & 15;
  // XCD-aware swizzle (bijective: 512 blocks, 8 XCDs; chunk = XCD id)
  const int orig = blockIdx.x;
  const int vid = (orig & 7) * 64 + (orig >> 3);
  const int chunk = vid >> 6, w = vid & 63;
  const int m0 = ((chunk & 3) * 8 + (w >> 3)) * 128;   // 32 m-blocks
  const int n0 = ((chunk >> 2) * 8 + (w & 7)) * 192;   // 16 n-blocks
  const int wn = wave * 48;                            // wave owns full 128 m x 48 n

  floatx4 acc[8][3];
#pragma unroll
  for (int i = 0; i < 8; ++i)
#pragma unroll
    for (int j = 0; j < 3; ++j) acc[i][j] = (floatx4){0.f, 0.f, 0.f, 0.f};

  const int srow = lane >> 3, sj = lane & 7;
  const int gj = (sj ^ srow) << 3;              // row&7 == srow for all staged rows

  const unsigned short* aSrc = A + (size_t)(m0 + wave * 32 + srow) * CC + gj;
  const unsigned short* bSrc = W + (size_t)(n0 + wave * 48 + srow) * CC + gj;

  auto stageT = [&](int buf) {
    char* la = (char*)lsA[buf] + (wave * 4) * 1024;
    char* lb = (char*)lsB[buf] + (wave * 6) * 1024;
#pragma unroll
    for (int rho = 0; rho < 4; ++rho)
      gload16(aSrc + (size_t)rho * 8 * CC, la + rho * 1024);
#pragma unroll
    for (int rho = 0; rho < 6; ++rho)
      gload16(bSrc + (size_t)rho * 8 * CC, lb + rho * 1024);
    aSrc += 64;
    bSrc += 64;
  };

  stageT(0);
  stageT(1);
  asm volatile("s_waitcnt vmcnt(10)" ::: "memory");  // tile0 landed; tile1 in flight
  barrier_fence();

#pragma unroll 2
  for (int t = 0; t < 16; ++t) {
    const int buf = t & 1;
    const char* la = (const char*)lsA[buf];
    const char* lb = (const char*)lsB[buf];
    short8 af[8][2], bfr[3][2];
#pragma unroll
    for (int i = 0; i < 8; ++i) {
      const int ra = i * 16 + c16;
#pragma unroll
      for (int kk = 0; kk < 2; ++kk) {
        const int ca = (kk * 4 + g) ^ (ra & 7);
        af[i][kk] = *reinterpret_cast<const short8*>(la + ra * 128 + (ca << 4));
      }
    }
#pragma unroll
    for (int j = 0; j < 3; ++j) {
      const int rb = wn + j * 16 + c16;
#pragma unroll
      for (int kk = 0; kk < 2; ++kk) {
        const int cb = (kk * 4 + g) ^ (rb & 7);
        bfr[j][kk] = *reinterpret_cast<const short8*>(lb + rb * 128 + (cb << 4));
      }
    }
    __builtin_amdgcn_s_setprio(1);
#pragma unroll
    for (int kk = 0; kk < 2; ++kk)
#pragma unroll
      for (int i = 0; i < 8; ++i)
#pragma unroll
        for (int j = 0; j < 3; ++j)
          acc[i][j] = __builtin_amdgcn_mfma_f32_16x16x32_bf16(af[i][kk], bfr[j][kk],
                                                              acc[i][j], 0, 0, 0);
    __builtin_amdgcn_s_setprio(0);
    if (t < 15) {
      barrier_fence();                                     // all done reading buf
      if (t < 14) {
        stageT(buf);                                       // refill just-freed buf (t+2)
        asm volatile("s_waitcnt vmcnt(10)" ::: "memory");  // t+1 certified
      } else {
        asm volatile("s_waitcnt vmcnt(0)" ::: "memory");   // tail: t15 certified
      }
      barrier_fence();
    }
  }

  // epilogue: per-fragment segment routing (192-tiles straddle 1024 boundaries)
  const int rgrp = g * 4;
#pragma unroll
  for (int i = 0; i < 8; ++i) {
    const int tk0 = m0 + i * 16 + rgrp;             // 4-aligned token base
    const int bb = tk0 >> 11;
    const int tw = tk0 & 2047;
    const int tpos = (tw & ~63) + perm64(tw & 63);
#pragma unroll
    for (int j = 0; j < 3; ++j) {
      const int gn = n0 + wn + j * 16 + c16;
      const int seg = gn >> 10;
      const float bv = ((seg == 0) ? b0 : (seg == 1) ? b1 : b2)[gn & 1023] *
                       ((seg == 0) ? QSCALE : 1.0f);
      if (gn >= 2048) {
        const int vdim = gn - 2048;
        const int h = vdim >> 6, d = vdim & 63;
        ushortx4 ov;
#pragma unroll
        for (int r = 0; r < 4; ++r) ov[r] = f2bf(acc[i][j][r] + bv);
        *reinterpret_cast<ushortx4*>(
            &Vt[((size_t)((bb * NH + h) * HD + d)) * TT + tpos]) = ov;
      } else {
#pragma unroll
        for (int r = 0; r < 4; ++r)
          out[(size_t)(tk0 + r) * QKVN + gn] = f2bf(acc[i][j][r] + bv);
      }
    }
  }
}

// ---------------- proj GEMM: 128x64 tile, grid 512 = 2 blocks/CU (8 waves/CU) ---------
__global__ __launch_bounds__(256) void gemm_proj(const unsigned short* __restrict__ A,
                                                 const unsigned short* __restrict__ W,
                                                 const float* __restrict__ bias,
                                                 float* __restrict__ outv) {
  __shared__ unsigned short lsA[2][128 * 64];
  __shared__ unsigned short lsB[2][64 * 64];
  const int tid = threadIdx.x;
  const int wave = tid >> 6, lane = tid & 63;
  const int orig = blockIdx.x;
  const int vid = (orig & 7) * 64 + (orig >> 3);   // bijective, 512 blocks / 8 XCDs
  const int m0 = (vid >> 4) * 128;                 // 32 m-blocks
  const int n0 = (vid & 15) * 64;                  // 16 n-blocks
  const int wm = (wave >> 1) * 64, wn = (wave & 1) * 32;
  const int K = CC, N = CC;

  floatx4 acc[4][2];
#pragma unroll
  for (int i = 0; i < 4; ++i)
#pragma unroll
    for (int j = 0; j < 2; ++j)
      acc[i][j] = (floatx4){0.f, 0.f, 0.f, 0.f};

  const int sr = lane >> 3;
  const int sj = lane & 7;
  const int gj = (sj ^ sr) << 3;

  const unsigned short* aSrc = A + (size_t)(m0 + wave * 32 + sr) * K + gj;
  const unsigned short* bSrc = W + (size_t)(n0 + wave * 16 + sr) * K + gj;

  auto stageT = [&](int buf) {
    char* la = (char*)lsA[buf] + (wave * 4) * 1024;
    char* lb = (char*)lsB[buf] + (wave * 2) * 1024;
#pragma unroll
    for (int rho = 0; rho < 4; ++rho)
      gload16(aSrc + (size_t)rho * 8 * K, la + rho * 1024);
#pragma unroll
    for (int rho = 0; rho < 2; ++rho)
      gload16(bSrc + (size_t)rho * 8 * K, lb + rho * 1024);
    aSrc += 64;
    bSrc += 64;
  };

  stageT(0);
  stageT(1);
  asm volatile("s_waitcnt vmcnt(6)" ::: "memory");
  barrier_fence();

#pragma unroll 2
  for (int t = 0; t < 16; ++t) {
    const int buf = t & 1;
    const char* la = (const char*)lsA[buf];
    const char* lb = (const char*)lsB[buf];
    short8 af[4][2], bfr[2][2];
#pragma unroll
    for (int i = 0; i < 4; ++i) {
      const int ra = wm + i * 16 + (lane & 15);
#pragma unroll
      for (int kk = 0; kk < 2; ++kk) {
        const int ca = (kk * 4 + (lane >> 4)) ^ (ra & 7);
        af[i][kk] = *reinterpret_cast<const short8*>(la + ra * 128 + (ca << 4));
      }
    }
#pragma unroll
    for (int j = 0; j < 2; ++j) {
      const int rb = wn + j * 16 + (lane & 15);
#pragma unroll
      for (int kk = 0; kk < 2; ++kk) {
        const int cb = (kk * 4 + (lane >> 4)) ^ (rb & 7);
        bfr[j][kk] = *reinterpret_cast<const short8*>(lb + rb * 128 + (cb << 4));
      }
    }
    __builtin_amdgcn_s_setprio(1);
#pragma unroll
    for (int kk = 0; kk < 2; ++kk)
#pragma unroll
      for (int i = 0; i < 4; ++i)
#pragma unroll
        for (int j = 0; j < 2; ++j)
          acc[i][j] = __builtin_amdgcn_mfma_f32_16x16x32_bf16(af[i][kk], bfr[j][kk],
                                                              acc[i][j], 0, 0, 0);
    __builtin_amdgcn_s_setprio(0);
    if (t < 15) {
      barrier_fence();
      if (t < 14) {
        stageT(buf);
        asm volatile("s_waitcnt vmcnt(6)" ::: "memory");
      } else {
        asm volatile("s_waitcnt vmcnt(0)" ::: "memory");
      }
      barrier_fence();
    }
  }

  const int col = lane & 15;
  const int rgrp = (lane >> 4) * 4;
#pragma unroll
  for (int i = 0; i < 4; ++i) {
    const int gm0 = m0 + wm + i * 16 + rgrp;
#pragma unroll
    for (int j = 0; j < 2; ++j) {
      const int gn = n0 + wn + j * 16 + col;
      const float bv = bias[gn];
#pragma unroll
      for (int r = 0; r < 4; ++r)
        outv[(size_t)(gm0 + r) * N + gn] = acc[i][j][r] + bv;
    }
  }
}

// ---------------- Flash attention: single-barrier/tile, K 2-deep (3 buf), V 1-deep ----
__global__ __launch_bounds__(256) void attn_fwd(const unsigned short* __restrict__ QKV,
                                                const unsigned short* __restrict__ Vt,
                                                unsigned short* __restrict__ Ob) {
  __shared__ unsigned short lsK[3][64 * 64];
  __shared__ unsigned short lsV[2][64 * 64];
  const int tid = threadIdx.x;
  const int wave = tid >> 6, lane = tid & 63;
  const int g = lane >> 4;
  const int c16 = lane & 15;
  const int bh = blockIdx.x;
  const int b = bh >> 4, h = bh & 15;
  const int q0 = blockIdx.y * 64 + wave * 16;

  short8 qf[2];
  {
    const unsigned short* qp =
        QKV + (size_t)(b * TT + q0 + c16) * QKVN + h * HD + g * 8;
    qf[0] = *reinterpret_cast<const short8*>(qp);
    qf[1] = *reinterpret_cast<const short8*>(qp + 32);
  }

  short8 ones;
#pragma unroll
  for (int i = 0; i < 8; ++i) ones[i] = (short)0x3F80;  // bf16 1.0

  floatx4 o[4];
#pragma unroll
  for (int f = 0; f < 4; ++f) o[f] = (floatx4){0.f, 0.f, 0.f, 0.f};
  floatx4 lacc = (floatx4){0.f, 0.f, 0.f, 0.f};

  const int sr = lane >> 3, sj = lane & 7;
  const int gj = (sj ^ sr) << 3;                // staged rows have row&7 == sr

  const unsigned short* kSrc =
      QKV + (size_t)(b * TT + wave * 16 + sr) * QKVN + CC + h * HD + gj;
  const unsigned short* vSrc = Vt + ((size_t)bh * HD + wave * 16 + sr) * TT + gj;

  auto stageK = [&](int buf) {
    char* lk = (char*)lsK[buf] + (wave * 2) * 1024;
    gload16(kSrc, lk);
    gload16(kSrc + (size_t)8 * QKVN, lk + 1024);
    kSrc += (size_t)64 * QKVN;
  };
  auto stageV = [&](int buf) {
    char* lv = (char*)lsV[buf] + (wave * 2) * 1024;
    gload16(vSrc, lv);
    gload16(vSrc + (size_t)8 * TT, lv + 1024);
    vSrc += 64;
  };

  auto compute = [&](const unsigned short* lk, const unsigned short* lv) {
    // S^T = K * Q^T  (log2 domain)
    floatx4 s[4];
#pragma unroll
    for (int cb = 0; cb < 4; ++cb) s[cb] = (floatx4){0.f, 0.f, 0.f, 0.f};
    __builtin_amdgcn_s_setprio(1);
#pragma unroll
    for (int kk = 0; kk < 2; ++kk) {
#pragma unroll
      for (int cb = 0; cb < 4; ++cb) {
        const int rk = cb * 16 + c16;
        const int ck = (kk * 4 + g) ^ (rk & 7);
        const short8 kf =
            *reinterpret_cast<const short8*>((const char*)lk + rk * 128 + (ck << 4));
        s[cb] = __builtin_amdgcn_mfma_f32_16x16x32_bf16(kf, qf[kk], s[cb], 0, 0, 0);
      }
    }
    __builtin_amdgcn_s_setprio(0);

    // P = 2^S and pack to bf16 pairs
    unsigned int w[4][2];
#pragma unroll
    for (int cb = 0; cb < 4; ++cb) {
#pragma unroll
      for (int r = 0; r < 4; ++r) s[cb][r] = fexp2(s[cb][r]);
      asm("v_cvt_pk_bf16_f32 %0, %1, %2"
          : "=v"(w[cb][0]) : "v"(s[cb][0]), "v"(s[cb][1]));
      asm("v_cvt_pk_bf16_f32 %0, %1, %2"
          : "=v"(w[cb][1]) : "v"(s[cb][2]), "v"(s[cb][3]));
    }

    // O^T += V^T * P^T ; l += ones * P^T (denominator on the matrix pipe)
#pragma unroll
    for (int kk = 0; kk < 2; ++kk) {
      unsigned int pa0 = w[2 * kk][0], pb0 = w[2 * kk + 1][0];
      unsigned int pa1 = w[2 * kk][1], pb1 = w[2 * kk + 1][1];
      asm("v_permlane32_swap_b32 %0, %1" : "+v"(pa0), "+v"(pb0));
      asm("v_permlane32_swap_b32 %0, %1" : "+v"(pa1), "+v"(pb1));
      union { unsigned int u[4]; short8 v; } pk;
      pk.u[0] = pa0; pk.u[1] = pa1; pk.u[2] = pb0; pk.u[3] = pb1;
      const short8 pbv = pk.v;
      __builtin_amdgcn_s_setprio(1);
#pragma unroll
      for (int f = 0; f < 4; ++f) {
        const int rv = f * 16 + c16;
        const int cv = (4 * kk + g) ^ (rv & 7);
        const short8 vf =
            *reinterpret_cast<const short8*>((const char*)lv + rv * 128 + (cv << 4));
        o[f] = __builtin_amdgcn_mfma_f32_16x16x32_bf16(vf, pbv, o[f], 0, 0, 0);
      }
      lacc = __builtin_amdgcn_mfma_f32_16x16x32_bf16(ones, pbv, lacc, 0, 0, 0);
      __builtin_amdgcn_s_setprio(0);
    }
  };

  // prologue: V(0), K(0), K(1) (V first -> drain order at it0 works out)
  stageV(0);
  stageK(0);
  stageK(1);

#pragma unroll 2
  for (int it = 0; it < TT / 64; ++it) {
    if (it < TT / 64 - 1)
      asm volatile("s_waitcnt vmcnt(2)" ::: "memory");    // K(t),V(t) certified;
    else                                                  // K(t+1) stays in flight
      asm volatile("s_waitcnt vmcnt(0)" ::: "memory");
    barrier_fence();   // all waves: tile-t landed; compute(t-1) done; stages pinned below
    if (it + 1 < TT / 64) stageV((it + 1) & 1);           // over V(t-1), consumed
    if (it + 2 < TT / 64) stageK((it + 2) % 3);           // over K(t-1), consumed
    compute((const unsigned short*)lsK[it % 3], (const unsigned short*)lsV[it & 1]);
  }

  // epilogue: normalize, vectorized 8B stores
  {
    const float inv = 1.0f / lacc[0];
    const size_t gm = (size_t)(b * TT + q0 + c16) * CC;
#pragma unroll
    for (int f = 0; f < 4; ++f) {
      ushortx4 ov;
#pragma unroll
      for (int r = 0; r < 4; ++r) ov[r] = f2bf(o[f][r] * inv);
      *reinterpret_cast<ushortx4*>(&Ob[gm + h * HD + f * 16 + 4 * g]) = ov;
    }
  }
}

extern "C" void kernel_launch(void* const* d_in, const int* in_sizes, int n_in,
                              void* d_out, int out_size, void* d_ws, size_t ws_size,
                              hipStream_t stream) {
  (void)in_sizes; (void)n_in; (void)out_size; (void)ws_size;
  const float* x  = (const float*)d_in[0];
  const float* Wk = (const float*)d_in[1];
  const float* bk = (const float*)d_in[2];
  const float* Wq = (const float*)d_in[3];
  const float* bq = (const float*)d_in[4];
  const float* Wv = (const float*)d_in[5];
  const float* bv = (const float*)d_in[6];
  const float* Wp = (const float*)d_in[7];
  const float* bp = (const float*)d_in[8];
  float* out = (float*)d_out;

  char* ws = (char*)d_ws;
  const size_t MB = 1u << 20;
  unsigned short* xb    = (unsigned short*)(ws);            // 8 MB [4096][1024]
  unsigned short* Wqkvb = (unsigned short*)(ws + 8 * MB);   // 6 MB [3072][1024] (q,k,v)
  unsigned short* Wpb   = (unsigned short*)(ws + 14 * MB);  // 2 MB
  unsigned short* QKVb  = (unsigned short*)(ws + 16 * MB);  // 24 MB [4096][3072] (V third unused)
  unsigned short* Vtb   = (unsigned short*)(ws + 40 * MB);  // 8 MB [32][64][2048] permuted
  unsigned short* Ab    = (unsigned short*)(ws + 48 * MB);  // 8 MB [4096][1024]

  cvt_fused<<<2048, 256, 0, stream>>>(x, Wq, Wk, Wv, Wp, xb, Wqkvb, Wpb);

  // fused QKV GEMM (128x192, 512 blocks = 2/CU, XCD-chunked); V third -> permuted Vt
  gemm_qkv<<<512, 256, 0, stream>>>(xb, Wqkvb, bq, bk, bv, QKVb, Vtb);

  // bh on blockIdx.x: all q-chunks of one bh share an XCD -> K/V L2 locality
  attn_fwd<<<dim3(2 * NH, TT / 64), 256, 0, stream>>>(QKVb, Vtb, Ab);

  // proj: 128x64 tiles, 512 blocks = 2/CU for latency hiding
  gemm_proj<<<512, 256, 0, stream>>>(Ab, Wpb, bp, out);
}

// Round 21
// 111.612 us; speedup vs baseline: 1.1532x; 1.1532x over previous
//
#include <hip/hip_runtime.h>
#include <hip/hip_bf16.h>
#include <stdint.h>

#define TT 2048
#define CC 1024
#define NH 16
#define HD 64
#define QKVN 3072

typedef __attribute__((ext_vector_type(8))) short short8;
typedef __attribute__((ext_vector_type(4))) float floatx4;
typedef __attribute__((ext_vector_type(4))) unsigned short ushortx4;

typedef const __attribute__((address_space(1))) void gas_void;
typedef __attribute__((address_space(3))) void las_void;

// s_barrier that is ALSO a compiler memory fence (raw builtin is not -- R17 race).
__device__ __forceinline__ void barrier_fence() {
  asm volatile("s_barrier" ::: "memory");
}

__device__ __forceinline__ void gload16(const void* g, void* l) {
  __builtin_amdgcn_global_load_lds((gas_void*)g, (las_void*)l, 16, 0, 0);
}

__device__ __forceinline__ unsigned short f2bf(float f) {
  union { float f; uint32_t u; } v; v.f = f;
  uint32_t u = v.u;
  uint32_t r = (u + 0x7fffu + ((u >> 16) & 1u)) >> 16;
  return (unsigned short)r;
}

__device__ __forceinline__ float fexp2(float x) {
#if __has_builtin(__builtin_amdgcn_exp2f)
  return __builtin_amdgcn_exp2f(x);
#else
  return exp2f(x);
#endif
}

#define QSCALE 0.18033688011112042f  // (1/8)*log2(e), folded into Wq/bq

// kv permutation within a 64-block: chunk c'=4kk+g holds runs [kA..kA+3, kA+8..kA+11]
__device__ __forceinline__ int perm64(int t) {
  const int kk = t >> 5, r5 = t & 31;
  const int g = ((r5 >> 3) & 2) | ((r5 >> 2) & 1);
  const int slot = (r5 & 3) | ((r5 >> 1) & 4);
  return kk * 32 + g * 8 + slot;
}

// ---------------- fused f32 -> bf16 conversion (grid-stride); Wq pre-scaled -----------
__global__ __launch_bounds__(256) void cvt_fused(const float* __restrict__ x,
                                                 const float* __restrict__ wq,
                                                 const float* __restrict__ wk,
                                                 const float* __restrict__ wv,
                                                 const float* __restrict__ wp,
                                                 unsigned short* __restrict__ xb,
                                                 unsigned short* __restrict__ wqkvb,
                                                 unsigned short* __restrict__ wpb) {
  for (int i = blockIdx.x * 256 + threadIdx.x; i < 2097152; i += 2048 * 256) {
    if (i < 1048576) {            // x: 4096x1024
      const float4 v = reinterpret_cast<const float4*>(x)[i];
      ushortx4 o; o[0] = f2bf(v.x); o[1] = f2bf(v.y); o[2] = f2bf(v.z); o[3] = f2bf(v.w);
      reinterpret_cast<ushortx4*>(xb)[i] = o;
      continue;
    }
    const int j = i - 1048576;     // 0..1048575 over 4 weight matrices
    const int seg = j >> 18;       // 262144 f4 per weight
    const int idx = j & 262143;
    const float* src = (seg == 0) ? wq : (seg == 1) ? wk : (seg == 2) ? wv : wp;
    const float sc = (seg == 0) ? QSCALE : 1.0f;
    const float4 v = reinterpret_cast<const float4*>(src)[idx];
    ushortx4 o;
    o[0] = f2bf(v.x * sc); o[1] = f2bf(v.y * sc); o[2] = f2bf(v.z * sc); o[3] = f2bf(v.w * sc);
    if (seg < 3)
      reinterpret_cast<ushortx4*>(wqkvb)[j] = o;       // q,k,v contiguous thirds
    else
      reinterpret_cast<ushortx4*>(wpb)[idx] = o;
  }
}

// ---------------- QKV GEMM: 256x192 tile, grid 256, XCD-chunk swizzle -----------------
// Counted-vmcnt 2-deep pipeline (two barriers/tile, vmcnt(7)), pointer-hoisted staging.
__global__ __launch_bounds__(512) void gemm_qkv(const unsigned short* __restrict__ A,
                                                const unsigned short* __restrict__ W,
                                                const float* __restrict__ b0,
                                                const float* __restrict__ b1,
                                                const float* __restrict__ b2,
                                                unsigned short* __restrict__ out,
                                                unsigned short* __restrict__ Vt) {
  __shared__ unsigned short lsA[2][256 * 64];
  __shared__ unsigned short lsB[2][192 * 64];
  const int tid = threadIdx.x;
  const int wave = tid >> 6, lane = tid & 63;
  const int g = lane >> 4, c16 = lane & 15;
  // XCD-aware swizzle (bijective: 256 blocks, 8 XCDs)
  const int orig = blockIdx.x;
  const int vid = (orig & 7) * 32 + (orig >> 3);
  const int chk = vid >> 5, wrm = vid & 31;
  const int m0 = ((chk & 3) * 4 + (wrm & 3)) * 256;
  const int n0 = ((chk >> 2) * 8 + (wrm >> 2)) * 192;
  const int wm = (wave >> 2) * 128, wn = (wave & 3) * 48;

  floatx4 acc[8][3];
#pragma unroll
  for (int i = 0; i < 8; ++i)
#pragma unroll
    for (int j = 0; j < 3; ++j) acc[i][j] = (floatx4){0.f, 0.f, 0.f, 0.f};

  const int srow = lane >> 3, sj = lane & 7;
  const int gj = (sj ^ srow) << 3;              // row&7 == srow for all staged rows

  const unsigned short* aSrc = A + (size_t)(m0 + wave * 32 + srow) * CC + gj;
  const unsigned short* bSrc = W + (size_t)(n0 + wave * 24 + srow) * CC + gj;

  auto stageT = [&](int buf) {
    char* la = (char*)lsA[buf] + (wave * 4) * 1024;
    char* lb = (char*)lsB[buf] + (wave * 3) * 1024;
#pragma unroll
    for (int rho = 0; rho < 4; ++rho)
      gload16(aSrc + (size_t)rho * 8 * CC, la + rho * 1024);
#pragma unroll
    for (int rho = 0; rho < 3; ++rho)
      gload16(bSrc + (size_t)rho * 8 * CC, lb + rho * 1024);
    aSrc += 64;
    bSrc += 64;
  };

  stageT(0);
  stageT(1);
  asm volatile("s_waitcnt vmcnt(7)" ::: "memory");   // tile0 landed; tile1 in flight
  barrier_fence();

#pragma unroll 2
  for (int t = 0; t < 16; ++t) {
    const int buf = t & 1;
    const char* la = (const char*)lsA[buf];
    const char* lb = (const char*)lsB[buf];
    short8 af[8][2], bfr[3][2];
#pragma unroll
    for (int i = 0; i < 8; ++i) {
      const int ra = wm + i * 16 + c16;
#pragma unroll
      for (int kk = 0; kk < 2; ++kk) {
        const int ca = (kk * 4 + g) ^ (ra & 7);
        af[i][kk] = *reinterpret_cast<const short8*>(la + ra * 128 + (ca << 4));
      }
    }
#pragma unroll
    for (int j = 0; j < 3; ++j) {
      const int rb = wn + j * 16 + c16;
#pragma unroll
      for (int kk = 0; kk < 2; ++kk) {
        const int cb = (kk * 4 + g) ^ (rb & 7);
        bfr[j][kk] = *reinterpret_cast<const short8*>(lb + rb * 128 + (cb << 4));
      }
    }
    __builtin_amdgcn_s_setprio(1);
#pragma unroll
    for (int kk = 0; kk < 2; ++kk)
#pragma unroll
      for (int i = 0; i < 8; ++i)
#pragma unroll
        for (int j = 0; j < 3; ++j)
          acc[i][j] = __builtin_amdgcn_mfma_f32_16x16x32_bf16(af[i][kk], bfr[j][kk],
                                                              acc[i][j], 0, 0, 0);
    __builtin_amdgcn_s_setprio(0);
    if (t < 15) {
      barrier_fence();                                    // all done reading buf
      if (t < 14) {
        stageT(buf);                                      // refill just-freed buf (t+2)
        asm volatile("s_waitcnt vmcnt(7)" ::: "memory");  // t+1 certified
      } else {
        asm volatile("s_waitcnt vmcnt(0)" ::: "memory");  // tail: t15 certified
      }
      barrier_fence();
    }
  }

  // epilogue: per-fragment segment routing (192-tiles straddle 1024 boundaries)
  const int rgrp = g * 4;
#pragma unroll
  for (int i = 0; i < 8; ++i) {
    const int tk0 = m0 + wm + i * 16 + rgrp;        // 4-aligned token base
    const int bb = tk0 >> 11;
    const int tw = tk0 & 2047;
    const int tpos = (tw & ~63) + perm64(tw & 63);
#pragma unroll
    for (int j = 0; j < 3; ++j) {
      const int gn = n0 + wn + j * 16 + c16;
      const int seg = gn >> 10;
      const float bv = ((seg == 0) ? b0 : (seg == 1) ? b1 : b2)[gn & 1023] *
                       ((seg == 0) ? QSCALE : 1.0f);
      if (gn >= 2048) {
        const int vdim = gn - 2048;
        const int h = vdim >> 6, d = vdim & 63;
        ushortx4 ov;
#pragma unroll
        for (int r = 0; r < 4; ++r) ov[r] = f2bf(acc[i][j][r] + bv);
        *reinterpret_cast<ushortx4*>(
            &Vt[((size_t)((bb * NH + h) * HD + d)) * TT + tpos]) = ov;
      } else {
#pragma unroll
        for (int r = 0; r < 4; ++r)
          out[(size_t)(tk0 + r) * QKVN + gn] = f2bf(acc[i][j][r] + bv);
      }
    }
  }
}

// ---------------- proj GEMM: 128x64 tile, grid 512 = 2 blocks/CU (8 waves/CU) ---------
// 4 waves 2x2; per-wave 64x32 (acc 4x2). LDS 48 KB double-buffered. Counted-vmcnt
// 2-deep (vmcnt(6)). XCD chunking: vid=(orig&7)*64+orig>>3 -> per-XCD A 1MB + B 2MB.
__global__ __launch_bounds__(256) void gemm_proj(const unsigned short* __restrict__ A,
                                                 const unsigned short* __restrict__ W,
                                                 const float* __restrict__ bias,
                                                 float* __restrict__ outv) {
  __shared__ unsigned short lsA[2][128 * 64];
  __shared__ unsigned short lsB[2][64 * 64];
  const int tid = threadIdx.x;
  const int wave = tid >> 6, lane = tid & 63;
  const int orig = blockIdx.x;
  const int vid = (orig & 7) * 64 + (orig >> 3);   // bijective, 512 blocks / 8 XCDs
  const int m0 = (vid >> 4) * 128;                 // 32 m-blocks
  const int n0 = (vid & 15) * 64;                  // 16 n-blocks
  const int wm = (wave >> 1) * 64, wn = (wave & 1) * 32;
  const int K = CC, N = CC;

  floatx4 acc[4][2];
#pragma unroll
  for (int i = 0; i < 4; ++i)
#pragma unroll
    for (int j = 0; j < 2; ++j)
      acc[i][j] = (floatx4){0.f, 0.f, 0.f, 0.f};

  const int sr = lane >> 3;
  const int sj = lane & 7;
  const int gj = (sj ^ sr) << 3;

  const unsigned short* aSrc = A + (size_t)(m0 + wave * 32 + sr) * K + gj;
  const unsigned short* bSrc = W + (size_t)(n0 + wave * 16 + sr) * K + gj;

  auto stageT = [&](int buf) {
    char* la = (char*)lsA[buf] + (wave * 4) * 1024;
    char* lb = (char*)lsB[buf] + (wave * 2) * 1024;
#pragma unroll
    for (int rho = 0; rho < 4; ++rho)
      gload16(aSrc + (size_t)rho * 8 * K, la + rho * 1024);
#pragma unroll
    for (int rho = 0; rho < 2; ++rho)
      gload16(bSrc + (size_t)rho * 8 * K, lb + rho * 1024);
    aSrc += 64;
    bSrc += 64;
  };

  stageT(0);
  stageT(1);
  asm volatile("s_waitcnt vmcnt(6)" ::: "memory");
  barrier_fence();

#pragma unroll 2
  for (int t = 0; t < 16; ++t) {
    const int buf = t & 1;
    const char* la = (const char*)lsA[buf];
    const char* lb = (const char*)lsB[buf];
    short8 af[4][2], bfr[2][2];
#pragma unroll
    for (int i = 0; i < 4; ++i) {
      const int ra = wm + i * 16 + (lane & 15);
#pragma unroll
      for (int kk = 0; kk < 2; ++kk) {
        const int ca = (kk * 4 + (lane >> 4)) ^ (ra & 7);
        af[i][kk] = *reinterpret_cast<const short8*>(la + ra * 128 + (ca << 4));
      }
    }
#pragma unroll
    for (int j = 0; j < 2; ++j) {
      const int rb = wn + j * 16 + (lane & 15);
#pragma unroll
      for (int kk = 0; kk < 2; ++kk) {
        const int cb = (kk * 4 + (lane >> 4)) ^ (rb & 7);
        bfr[j][kk] = *reinterpret_cast<const short8*>(lb + rb * 128 + (cb << 4));
      }
    }
    __builtin_amdgcn_s_setprio(1);
#pragma unroll
    for (int kk = 0; kk < 2; ++kk)
#pragma unroll
      for (int i = 0; i < 4; ++i)
#pragma unroll
        for (int j = 0; j < 2; ++j)
          acc[i][j] = __builtin_amdgcn_mfma_f32_16x16x32_bf16(af[i][kk], bfr[j][kk],
                                                              acc[i][j], 0, 0, 0);
    __builtin_amdgcn_s_setprio(0);
    if (t < 15) {
      barrier_fence();
      if (t < 14) {
        stageT(buf);
        asm volatile("s_waitcnt vmcnt(6)" ::: "memory");
      } else {
        asm volatile("s_waitcnt vmcnt(0)" ::: "memory");
      }
      barrier_fence();
    }
  }

  const int col = lane & 15;
  const int rgrp = (lane >> 4) * 4;
#pragma unroll
  for (int i = 0; i < 4; ++i) {
    const int gm0 = m0 + wm + i * 16 + rgrp;
#pragma unroll
    for (int j = 0; j < 2; ++j) {
      const int gn = n0 + wn + j * 16 + col;
      const float bv = bias[gn];
#pragma unroll
      for (int r = 0; r < 4; ++r)
        outv[(size_t)(gm0 + r) * N + gn] = acc[i][j][r] + bv;
    }
  }
}

// ---------------- Flash attention: single-barrier/tile, K 2-deep (3 buf), V 1-deep ----
// Grid (B*H, T/64): bh on blockIdx.x -> each bh's K/V pinned to one XCD L2.
// 4 waves; wave owns 16 q rows. Q pre-scaled by (1/8)log2e -> S log2-domain,
// P=2^S bounded, no running max. l via mfma(ones,P).
__global__ __launch_bounds__(256) void attn_fwd(const unsigned short* __restrict__ QKV,
                                                const unsigned short* __restrict__ Vt,
                                                unsigned short* __restrict__ Ob) {
  __shared__ unsigned short lsK[3][64 * 64];
  __shared__ unsigned short lsV[2][64 * 64];
  const int tid = threadIdx.x;
  const int wave = tid >> 6, lane = tid & 63;
  const int g = lane >> 4;
  const int c16 = lane & 15;
  const int bh = blockIdx.x;
  const int b = bh >> 4, h = bh & 15;
  const int q0 = blockIdx.y * 64 + wave * 16;

  short8 qf[2];
  {
    const unsigned short* qp =
        QKV + (size_t)(b * TT + q0 + c16) * QKVN + h * HD + g * 8;
    qf[0] = *reinterpret_cast<const short8*>(qp);
    qf[1] = *reinterpret_cast<const short8*>(qp + 32);
  }

  short8 ones;
#pragma unroll
  for (int i = 0; i < 8; ++i) ones[i] = (short)0x3F80;  // bf16 1.0

  floatx4 o[4];
#pragma unroll
  for (int f = 0; f < 4; ++f) o[f] = (floatx4){0.f, 0.f, 0.f, 0.f};
  floatx4 lacc = (floatx4){0.f, 0.f, 0.f, 0.f};

  const int sr = lane >> 3, sj = lane & 7;
  const int gj = (sj ^ sr) << 3;                // staged rows have row&7 == sr

  const unsigned short* kSrc =
      QKV + (size_t)(b * TT + wave * 16 + sr) * QKVN + CC + h * HD + gj;
  const unsigned short* vSrc = Vt + ((size_t)bh * HD + wave * 16 + sr) * TT + gj;

  auto stageK = [&](int buf) {
    char* lk = (char*)lsK[buf] + (wave * 2) * 1024;
    gload16(kSrc, lk);
    gload16(kSrc + (size_t)8 * QKVN, lk + 1024);
    kSrc += (size_t)64 * QKVN;
  };
  auto stageV = [&](int buf) {
    char* lv = (char*)lsV[buf] + (wave * 2) * 1024;
    gload16(vSrc, lv);
    gload16(vSrc + (size_t)8 * TT, lv + 1024);
    vSrc += 64;
  };

  auto compute = [&](const unsigned short* lk, const unsigned short* lv) {
    // S^T = K * Q^T  (log2 domain)
    floatx4 s[4];
#pragma unroll
    for (int cb = 0; cb < 4; ++cb) s[cb] = (floatx4){0.f, 0.f, 0.f, 0.f};
    __builtin_amdgcn_s_setprio(1);
#pragma unroll
    for (int kk = 0; kk < 2; ++kk) {
#pragma unroll
      for (int cb = 0; cb < 4; ++cb) {
        const int rk = cb * 16 + c16;
        const int ck = (kk * 4 + g) ^ (rk & 7);
        const short8 kf =
            *reinterpret_cast<const short8*>((const char*)lk + rk * 128 + (ck << 4));
        s[cb] = __builtin_amdgcn_mfma_f32_16x16x32_bf16(kf, qf[kk], s[cb], 0, 0, 0);
      }
    }
    __builtin_amdgcn_s_setprio(0);

    // P = 2^S and pack to bf16 pairs
    unsigned int w[4][2];
#pragma unroll
    for (int cb = 0; cb < 4; ++cb) {
#pragma unroll
      for (int r = 0; r < 4; ++r) s[cb][r] = fexp2(s[cb][r]);
      asm("v_cvt_pk_bf16_f32 %0, %1, %2"
          : "=v"(w[cb][0]) : "v"(s[cb][0]), "v"(s[cb][1]));
      asm("v_cvt_pk_bf16_f32 %0, %1, %2"
          : "=v"(w[cb][1]) : "v"(s[cb][2]), "v"(s[cb][3]));
    }

    // O^T += V^T * P^T ; l += ones * P^T (denominator on the matrix pipe)
#pragma unroll
    for (int kk = 0; kk < 2; ++kk) {
      unsigned int pa0 = w[2 * kk][0], pb0 = w[2 * kk + 1][0];
      unsigned int pa1 = w[2 * kk][1], pb1 = w[2 * kk + 1][1];
      asm("v_permlane32_swap_b32 %0, %1" : "+v"(pa0), "+v"(pb0));
      asm("v_permlane32_swap_b32 %0, %1" : "+v"(pa1), "+v"(pb1));
      union { unsigned int u[4]; short8 v; } pk;
      pk.u[0] = pa0; pk.u[1] = pa1; pk.u[2] = pb0; pk.u[3] = pb1;
      const short8 pbv = pk.v;
      __builtin_amdgcn_s_setprio(1);
#pragma unroll
      for (int f = 0; f < 4; ++f) {
        const int rv = f * 16 + c16;
        const int cv = (4 * kk + g) ^ (rv & 7);
        const short8 vf =
            *reinterpret_cast<const short8*>((const char*)lv + rv * 128 + (cv << 4));
        o[f] = __builtin_amdgcn_mfma_f32_16x16x32_bf16(vf, pbv, o[f], 0, 0, 0);
      }
      lacc = __builtin_amdgcn_mfma_f32_16x16x32_bf16(ones, pbv, lacc, 0, 0, 0);
      __builtin_amdgcn_s_setprio(0);
    }
  };

  // prologue: V(0), K(0), K(1) (V first -> drain order at it0 works out)
  stageV(0);
  stageK(0);
  stageK(1);

#pragma unroll 2
  for (int it = 0; it < TT / 64; ++it) {
    if (it < TT / 64 - 1)
      asm volatile("s_waitcnt vmcnt(2)" ::: "memory");    // K(t),V(t) certified;
    else                                                  // K(t+1) stays in flight
      asm volatile("s_waitcnt vmcnt(0)" ::: "memory");
    barrier_fence();   // all waves: tile-t landed; compute(t-1) done; stages pinned below
    if (it + 1 < TT / 64) stageV((it + 1) & 1);           // over V(t-1), consumed
    if (it + 2 < TT / 64) stageK((it + 2) % 3);           // over K(t-1), consumed
    compute((const unsigned short*)lsK[it % 3], (const unsigned short*)lsV[it & 1]);
  }

  // epilogue: normalize, vectorized 8B stores
  {
    const float inv = 1.0f / lacc[0];
    const size_t gm = (size_t)(b * TT + q0 + c16) * CC;
#pragma unroll
    for (int f = 0; f < 4; ++f) {
      ushortx4 ov;
#pragma unroll
      for (int r = 0; r < 4; ++r) ov[r] = f2bf(o[f][r] * inv);
      *reinterpret_cast<ushortx4*>(&Ob[gm + h * HD + f * 16 + 4 * g]) = ov;
    }
  }
}

extern "C" void kernel_launch(void* const* d_in, const int* in_sizes, int n_in,
                              void* d_out, int out_size, void* d_ws, size_t ws_size,
                              hipStream_t stream) {
  (void)in_sizes; (void)n_in; (void)out_size; (void)ws_size;
  const float* x  = (const float*)d_in[0];
  const float* Wk = (const float*)d_in[1];
  const float* bk = (const float*)d_in[2];
  const float* Wq = (const float*)d_in[3];
  const float* bq = (const float*)d_in[4];
  const float* Wv = (const float*)d_in[5];
  const float* bv = (const float*)d_in[6];
  const float* Wp = (const float*)d_in[7];
  const float* bp = (const float*)d_in[8];
  float* out = (float*)d_out;

  char* ws = (char*)d_ws;
  const size_t MB = 1u << 20;
  unsigned short* xb    = (unsigned short*)(ws);            // 8 MB [4096][1024]
  unsigned short* Wqkvb = (unsigned short*)(ws + 8 * MB);   // 6 MB [3072][1024] (q,k,v)
  unsigned short* Wpb   = (unsigned short*)(ws + 14 * MB);  // 2 MB
  unsigned short* QKVb  = (unsigned short*)(ws + 16 * MB);  // 24 MB [4096][3072] (V third unused)
  unsigned short* Vtb   = (unsigned short*)(ws + 40 * MB);  // 8 MB [32][64][2048] permuted
  unsigned short* Ab    = (unsigned short*)(ws + 48 * MB);  // 8 MB [4096][1024]

  cvt_fused<<<2048, 256, 0, stream>>>(x, Wq, Wk, Wv, Wp, xb, Wqkvb, Wpb);

  // fused QKV GEMM (256x192, 256 blocks = 1/CU, XCD-chunked); V third -> permuted Vt
  gemm_qkv<<<256, 512, 0, stream>>>(xb, Wqkvb, bq, bk, bv, QKVb, Vtb);

  // bh on blockIdx.x: all q-chunks of one bh share an XCD -> K/V L2 locality
  attn_fwd<<<dim3(2 * NH, TT / 64), 256, 0, stream>>>(QKVb, Vtb, Ab);

  // proj: 128x64 tiles, 512 blocks = 2/CU for latency hiding
  gemm_proj<<<512, 256, 0, stream>>>(Ab, Wpb, bp, out);
}